// Round 1
// baseline (693.598 us; speedup 1.0000x reference)
//
#include <hip/hip_runtime.h>
#include <cstdint>
#include <cstddef>

#define B_    8
#define N1_   1024
#define N2_   4096
#define C1_   256
#define C2_   128
#define CS_   64
#define CT_   448
#define H_    256
#define ROWS_ (B_ * N2_)   // 32768

// ---------------------------------------------------------------- KNN (K=3)
__global__ __launch_bounds__(256) void knn_kernel(
    const float* __restrict__ p1, const float* __restrict__ p2,
    int* __restrict__ ind, float* __restrict__ wout)
{
#pragma clang fp contract(off)
    __shared__ float sx[N1_], sy[N1_], sz[N1_], ss[N1_];
    const int b = blockIdx.x >> 4;                       // 16 chunks of 256 per batch
    const int n = ((blockIdx.x & 15) << 8) + threadIdx.x; // 0..4095 within batch
    const float* pb1 = p1 + (size_t)b * 3 * N1_;
    for (int i = threadIdx.x; i < N1_; i += 256) {
        float X = pb1[i], Y = pb1[N1_ + i], Z = pb1[2 * N1_ + i];
        sx[i] = X; sy[i] = Y; sz[i] = Z;
        ss[i] = (X * X + Y * Y) + Z * Z;
    }
    __syncthreads();
    const float* pb2 = p2 + (size_t)b * 3 * N2_;
    const float qx = pb2[n], qy = pb2[N2_ + n], qz = pb2[2 * N2_ + n];
    const float s2 = (qx * qx + qy * qy) + qz * qz;
    float d0 = 3.0e38f, d1 = 3.0e38f, d2v = 3.0e38f;
    int   i0 = 0, i1 = 0, i2 = 0;
    for (int i = 0; i < N1_; ++i) {
        float dot = (qx * sx[i] + qy * sy[i]) + qz * sz[i];
        float dd  = (s2 + ss[i]) - 2.0f * dot;
        float d   = sqrtf(fmaxf(dd, 0.0f));
        if (d < d0)       { d2v = d1; i2 = i1; d1 = d0; i1 = i0; d0 = d; i0 = i; }
        else if (d < d1)  { d2v = d1; i2 = i1; d1 = d;  i1 = i; }
        else if (d < d2v) { d2v = d;  i2 = i; }
    }
    float inv0 = 1.0f / (d0 + 1e-10f);
    float inv1 = 1.0f / (d1 + 1e-10f);
    float inv2 = 1.0f / (d2v + 1e-10f);
    float s = (inv0 + inv1) + inv2;
    const size_t row = (size_t)b * N2_ + n;
    wout[row * 3 + 0] = inv0 / s;
    wout[row * 3 + 1] = inv1 / s;
    wout[row * 3 + 2] = inv2 / s;
    ind[row * 3 + 0] = i0;
    ind[row * 3 + 1] = i1;
    ind[row * 3 + 2] = i2;
}

// ------------------------------------------- interpolate + concat -> x[32768][448]
__global__ __launch_bounds__(448) void build_x_kernel(
    const float* __restrict__ f1, const float* __restrict__ f2,
    const float* __restrict__ fs, const int* __restrict__ ind,
    const float* __restrict__ w, float* __restrict__ x)
{
    const int row = blockIdx.x;
    const int b = row >> 12;
    const int n = row & (N2_ - 1);
    const int c = threadIdx.x;
    float v;
    if (c < C1_) {
        const int   i0 = ind[row * 3 + 0], i1 = ind[row * 3 + 1], i2 = ind[row * 3 + 2];
        const float w0 = w[row * 3 + 0],   w1 = w[row * 3 + 1],   w2 = w[row * 3 + 2];
        const float* fr = f1 + ((size_t)b * C1_ + c) * N1_;
        v = w0 * fr[i0] + w1 * fr[i1] + w2 * fr[i2];
    } else if (c < C1_ + C2_) {
        v = f2[((size_t)b * C2_ + (c - C1_)) * N2_ + n];
    } else {
        v = fs[((size_t)b * CS_ + (c - C1_ - C2_)) * N2_ + n];
    }
    x[(size_t)row * CT_ + c] = v;
}

// ------------------------------------------- fp32 GEMM: C[m,n] = A[m,:]·Bw[n,:] + bias[n]
__global__ __launch_bounds__(256) void gemm_nt(
    const float* __restrict__ A, const float* __restrict__ Bw,
    const float* __restrict__ bias, float* __restrict__ C,
    int M, int N, int Kd)
{
    __shared__ float As[16][68];
    __shared__ float Bs[16][68];
    const int tid = threadIdx.x;
    const int m0 = blockIdx.x * 64;
    const int n0 = blockIdx.y * 64;
    const int tx = tid & 15;          // 0..15 col group
    const int ty = tid >> 4;          // 0..15 row group
    const int lrow = tid >> 2;        // 0..63
    const int lk4 = (tid & 3) << 2;   // 0,4,8,12
    float acc[4][4] = {};
    for (int k0 = 0; k0 < Kd; k0 += 16) {
        float4 av = *(const float4*)(A  + (size_t)(m0 + lrow) * Kd + k0 + lk4);
        float4 bv = *(const float4*)(Bw + (size_t)(n0 + lrow) * Kd + k0 + lk4);
        __syncthreads();
        As[lk4 + 0][lrow] = av.x; As[lk4 + 1][lrow] = av.y;
        As[lk4 + 2][lrow] = av.z; As[lk4 + 3][lrow] = av.w;
        Bs[lk4 + 0][lrow] = bv.x; Bs[lk4 + 1][lrow] = bv.y;
        Bs[lk4 + 2][lrow] = bv.z; Bs[lk4 + 3][lrow] = bv.w;
        __syncthreads();
#pragma unroll
        for (int k = 0; k < 16; ++k) {
            float4 a = *(const float4*)&As[k][ty << 2];
            float4 b = *(const float4*)&Bs[k][tx << 2];
            acc[0][0] += a.x * b.x; acc[0][1] += a.x * b.y; acc[0][2] += a.x * b.z; acc[0][3] += a.x * b.w;
            acc[1][0] += a.y * b.x; acc[1][1] += a.y * b.y; acc[1][2] += a.y * b.z; acc[1][3] += a.y * b.w;
            acc[2][0] += a.z * b.x; acc[2][1] += a.z * b.y; acc[2][2] += a.z * b.z; acc[2][3] += a.z * b.w;
            acc[3][0] += a.w * b.x; acc[3][1] += a.w * b.y; acc[3][2] += a.w * b.z; acc[3][3] += a.w * b.w;
        }
    }
    const int cn = n0 + (tx << 2);
    const float bb0 = bias[cn + 0], bb1 = bias[cn + 1], bb2 = bias[cn + 2], bb3 = bias[cn + 3];
#pragma unroll
    for (int i = 0; i < 4; ++i) {
        float4 o;
        o.x = acc[i][0] + bb0; o.y = acc[i][1] + bb1;
        o.z = acc[i][2] + bb2; o.w = acc[i][3] + bb3;
        *(float4*)(C + (size_t)(m0 + (ty << 2) + i) * N + cn) = o;
    }
}

// ------------------------------------------- per-channel sum / sumsq (BN stats)
__global__ __launch_bounds__(256) void stats_kernel(
    const float* __restrict__ y, float* __restrict__ ssum, float* __restrict__ ssq)
{
    const int c = threadIdx.x;
    const size_t base = (size_t)blockIdx.x * 128 * H_;
    float s = 0.0f, q = 0.0f;
    for (int r = 0; r < 128; ++r) {
        float v = y[base + (size_t)r * H_ + c];
        s += v;
        q += v * v;
    }
    atomicAdd(&ssum[c], s);
    atomicAdd(&ssq[c], q);
}

// ------------------------------------------- BN + ReLU in place on y[32768][256]
__global__ __launch_bounds__(256) void bn_relu_kernel(
    float* __restrict__ y, const float* __restrict__ ssum, const float* __restrict__ ssq,
    const float* __restrict__ g, const float* __restrict__ beta)
{
    __shared__ float sc[H_], sh[H_];
    const float invN = 1.0f / (float)ROWS_;
    const int t = threadIdx.x;
    {
        float mu  = ssum[t] * invN;
        float var = ssq[t] * invN - mu * mu;
        float s   = rsqrtf(var + 1e-3f) * g[t];
        sc[t] = s;
        sh[t] = beta[t] - mu * s;
    }
    __syncthreads();
    const int c0 = (t << 2) & (H_ - 1);
    const float s0 = sc[c0], s1 = sc[c0 + 1], s2 = sc[c0 + 2], s3 = sc[c0 + 3];
    const float h0 = sh[c0], h1 = sh[c0 + 1], h2 = sh[c0 + 2], h3 = sh[c0 + 3];
    float4* yp = (float4*)y;
    const size_t base = (size_t)blockIdx.x * 1024 + t;
#pragma unroll
    for (int j = 0; j < 4; ++j) {
        float4 v = yp[base + j * 256];
        v.x = fmaxf(v.x * s0 + h0, 0.0f);
        v.y = fmaxf(v.y * s1 + h1, 0.0f);
        v.z = fmaxf(v.z * s2 + h2, 0.0f);
        v.w = fmaxf(v.w * s3 + h3, 0.0f);
        yp[base + j * 256] = v;
    }
}

// ------------------------------------------- BN + ReLU + transpose to out[B,256,N2]
__global__ __launch_bounds__(256) void bn_out_kernel(
    const float* __restrict__ y, const float* __restrict__ ssum, const float* __restrict__ ssq,
    const float* __restrict__ g, const float* __restrict__ beta, float* __restrict__ out)
{
    __shared__ float tile[64][65];
    __shared__ float sc[64], sh[64];
    const float invN = 1.0f / (float)ROWS_;
    const int bid = blockIdx.x;
    const int b  = bid >> 8;         // 256 blocks per batch (64 ntiles * 4 otiles)
    const int nt = (bid >> 2) & 63;
    const int ot = bid & 3;
    const int t = threadIdx.x;
    if (t < 64) {
        int c = ot * 64 + t;
        float mu  = ssum[c] * invN;
        float var = ssq[c] * invN - mu * mu;
        float s   = rsqrtf(var + 1e-3f) * g[c];
        sc[t] = s;
        sh[t] = beta[c] - mu * s;
    }
    __syncthreads();
    const int n0 = nt * 64, o0 = ot * 64;
    const float* yb = y + ((size_t)b * N2_ + n0) * H_ + o0;
#pragma unroll
    for (int j = 0; j < 16; ++j) {
        int lin = j * 256 + t;
        int nl = lin >> 6, ol = lin & 63;
        float v = yb[(size_t)nl * H_ + ol];
        tile[nl][ol] = fmaxf(v * sc[ol] + sh[ol], 0.0f);
    }
    __syncthreads();
    float* ob = out + ((size_t)b * H_ + o0) * N2_ + n0;
#pragma unroll
    for (int j = 0; j < 16; ++j) {
        int lin = j * 256 + t;
        int ol = lin >> 6, nl = lin & 63;
        ob[(size_t)ol * N2_ + nl] = tile[nl][ol];
    }
}

// ----------------------------------------------------------------------------
extern "C" void kernel_launch(void* const* d_in, const int* in_sizes, int n_in,
                              void* d_out, int out_size, void* d_ws, size_t ws_size,
                              hipStream_t stream)
{
    (void)in_sizes; (void)n_in; (void)out_size; (void)ws_size;
    const float* points1   = (const float*)d_in[0];
    const float* points2   = (const float*)d_in[1];
    const float* features1 = (const float*)d_in[2];
    const float* features2 = (const float*)d_in[3];
    const float* skipf     = (const float*)d_in[4];
    const float* W1  = (const float*)d_in[5];
    const float* b1  = (const float*)d_in[6];
    const float* g1  = (const float*)d_in[7];
    const float* be1 = (const float*)d_in[8];
    const float* W2  = (const float*)d_in[9];
    const float* b2  = (const float*)d_in[10];
    const float* g2  = (const float*)d_in[11];
    const float* be2 = (const float*)d_in[12];
    float* out = (float*)d_out;

    char* ws = (char*)d_ws;
    float* s1  = (float*)(ws + 0);
    float* q1  = (float*)(ws + 1024);
    float* s2  = (float*)(ws + 2048);
    float* q2  = (float*)(ws + 3072);
    int*   ind = (int*)  (ws + 4096);                      //  98304 ints
    float* wgt = (float*)(ws + 397312);                    //  98304 floats
    float* x   = (float*)(ws + 790528);                    //  32768*448 floats (58.7 MB)
    float* y1  = (float*)(ws + 59510784);                  //  32768*256 floats (33.6 MB)
    float* y2  = x;                                        //  alias: x dead after gemm1

    hipMemsetAsync(ws, 0, 4096, stream);                   // zero BN stats (ws is poisoned)

    knn_kernel<<<dim3(B_ * 16), dim3(256), 0, stream>>>(points1, points2, ind, wgt);
    build_x_kernel<<<dim3(ROWS_), dim3(448), 0, stream>>>(features1, features2, skipf, ind, wgt, x);

    gemm_nt<<<dim3(ROWS_ / 64, H_ / 64), dim3(256), 0, stream>>>(x, W1, b1, y1, ROWS_, H_, CT_);
    stats_kernel<<<dim3(256), dim3(256), 0, stream>>>(y1, s1, q1);
    bn_relu_kernel<<<dim3(2048), dim3(256), 0, stream>>>(y1, s1, q1, g1, be1);

    gemm_nt<<<dim3(ROWS_ / 64, H_ / 64), dim3(256), 0, stream>>>(y1, W2, b2, y2, ROWS_, H_, H_);
    stats_kernel<<<dim3(256), dim3(256), 0, stream>>>(y2, s2, q2);
    bn_out_kernel<<<dim3(2048), dim3(256), 0, stream>>>(y2, s2, q2, g2, be2, out);
}

// Round 2
// 509.423 us; speedup vs baseline: 1.3615x; 1.3615x over previous
//
#include <hip/hip_runtime.h>
#include <cstdint>
#include <cstddef>

#define B_    8
#define N1_   1024
#define N2_   4096
#define C1_   256
#define C2_   128
#define CS_   64
#define CT_   448
#define H_    256
#define ROWS_ (B_ * N2_)   // 32768

// ---------------------------------------------------------------- KNN (K=3)
// 512 blocks x 256 threads. Each block: 64 queries x 4 candidate-splits.
// Wave w (t>>6) = split w; all 64 lanes of a wave broadcast-read the same
// candidate float4 from LDS. Per-split top-3 merged via LDS (index-ordered
// splits + strict < keeps top_k's lowest-index tie-break).
__global__ __launch_bounds__(256) void knn_kernel(
    const float* __restrict__ p1, const float* __restrict__ p2,
    int* __restrict__ ind, float* __restrict__ wout)
{
#pragma clang fp contract(off)
    __shared__ float4 cand[N1_];       // 16 KB: x,y,z,|p|^2
    __shared__ float  pd[256][3];
    __shared__ int    pi[256][3];
    const int t = threadIdx.x;
    const int b = blockIdx.x >> 6;               // 64 blocks per batch
    const int qbase = (blockIdx.x & 63) * 64;    // 64 queries per block
    const float* pb1 = p1 + (size_t)b * 3 * N1_;
    for (int i = t; i < N1_; i += 256) {
        float X = pb1[i], Y = pb1[N1_ + i], Z = pb1[2 * N1_ + i];
        cand[i] = make_float4(X, Y, Z, (X * X + Y * Y) + Z * Z);
    }
    const int n = qbase + (t & 63);
    const int split = t >> 6;
    const float* pb2 = p2 + (size_t)b * 3 * N2_;
    const float qx = pb2[n], qy = pb2[N2_ + n], qz = pb2[2 * N2_ + n];
    const float s2 = (qx * qx + qy * qy) + qz * qz;
    __syncthreads();
    float d0 = 3.0e38f, d1 = 3.0e38f, d2v = 3.0e38f;
    int   i0 = 0, i1 = 0, i2 = 0;
    const int ibeg = split * (N1_ / 4);
    const int iend = ibeg + (N1_ / 4);
    for (int i = ibeg; i < iend; ++i) {
        float4 c = cand[i];
        float dot = (qx * c.x + qy * c.y) + qz * c.z;
        float dd  = (s2 + c.w) - 2.0f * dot;
        float d   = sqrtf(fmaxf(dd, 0.0f));
        if (d < d0)       { d2v = d1; i2 = i1; d1 = d0; i1 = i0; d0 = d; i0 = i; }
        else if (d < d1)  { d2v = d1; i2 = i1; d1 = d;  i1 = i; }
        else if (d < d2v) { d2v = d;  i2 = i; }
    }
    pd[t][0] = d0; pd[t][1] = d1; pd[t][2] = d2v;
    pi[t][0] = i0; pi[t][1] = i1; pi[t][2] = i2;
    __syncthreads();
    if (t < 64) {
        float e0 = 3.0e38f, e1 = 3.0e38f, e2 = 3.0e38f;
        int   j0 = 0, j1 = 0, j2 = 0;
#pragma unroll
        for (int s = 0; s < 4; ++s) {
            const int src = s * 64 + t;
#pragma unroll
            for (int r = 0; r < 3; ++r) {
                float d = pd[src][r];
                int   i = pi[src][r];
                if (d < e0)      { e2 = e1; j2 = j1; e1 = e0; j1 = j0; e0 = d; j0 = i; }
                else if (d < e1) { e2 = e1; j2 = j1; e1 = d;  j1 = i; }
                else if (d < e2) { e2 = d;  j2 = i; }
            }
        }
        float inv0 = 1.0f / (e0 + 1e-10f);
        float inv1 = 1.0f / (e1 + 1e-10f);
        float inv2 = 1.0f / (e2 + 1e-10f);
        float s = (inv0 + inv1) + inv2;
        const size_t row = (size_t)b * N2_ + qbase + t;
        wout[row * 3 + 0] = inv0 / s;
        wout[row * 3 + 1] = inv1 / s;
        wout[row * 3 + 2] = inv2 / s;
        ind[row * 3 + 0] = j0;
        ind[row * 3 + 1] = j1;
        ind[row * 3 + 2] = j2;
    }
}

// ------------------------------------------- interpolate + concat -> x[32768][448]
__global__ __launch_bounds__(448) void build_x_kernel(
    const float* __restrict__ f1, const float* __restrict__ f2,
    const float* __restrict__ fs, const int* __restrict__ ind,
    const float* __restrict__ w, float* __restrict__ x)
{
    const int row = blockIdx.x;
    const int b = row >> 12;
    const int n = row & (N2_ - 1);
    const int c = threadIdx.x;
    float v;
    if (c < C1_) {
        const int   i0 = ind[row * 3 + 0], i1 = ind[row * 3 + 1], i2 = ind[row * 3 + 2];
        const float w0 = w[row * 3 + 0],   w1 = w[row * 3 + 1],   w2 = w[row * 3 + 2];
        const float* fr = f1 + ((size_t)b * C1_ + c) * N1_;
        v = w0 * fr[i0] + w1 * fr[i1] + w2 * fr[i2];
    } else if (c < C1_ + C2_) {
        v = f2[((size_t)b * C2_ + (c - C1_)) * N2_ + n];
    } else {
        v = fs[((size_t)b * CS_ + (c - C1_ - C2_)) * N2_ + n];
    }
    x[(size_t)row * CT_ + c] = v;
}

// ------------------------------------------- fp32 GEMM: C[m,n] = A[m,:]·Bw[n,:] + bias[n]
__global__ __launch_bounds__(256) void gemm_nt(
    const float* __restrict__ A, const float* __restrict__ Bw,
    const float* __restrict__ bias, float* __restrict__ C,
    int M, int N, int Kd)
{
    __shared__ float As[16][68];
    __shared__ float Bs[16][68];
    const int tid = threadIdx.x;
    const int m0 = blockIdx.x * 64;
    const int n0 = blockIdx.y * 64;
    const int tx = tid & 15;          // 0..15 col group
    const int ty = tid >> 4;          // 0..15 row group
    const int lrow = tid >> 2;        // 0..63
    const int lk4 = (tid & 3) << 2;   // 0,4,8,12
    float acc[4][4] = {};
    for (int k0 = 0; k0 < Kd; k0 += 16) {
        float4 av = *(const float4*)(A  + (size_t)(m0 + lrow) * Kd + k0 + lk4);
        float4 bv = *(const float4*)(Bw + (size_t)(n0 + lrow) * Kd + k0 + lk4);
        __syncthreads();
        As[lk4 + 0][lrow] = av.x; As[lk4 + 1][lrow] = av.y;
        As[lk4 + 2][lrow] = av.z; As[lk4 + 3][lrow] = av.w;
        Bs[lk4 + 0][lrow] = bv.x; Bs[lk4 + 1][lrow] = bv.y;
        Bs[lk4 + 2][lrow] = bv.z; Bs[lk4 + 3][lrow] = bv.w;
        __syncthreads();
#pragma unroll
        for (int k = 0; k < 16; ++k) {
            float4 a = *(const float4*)&As[k][ty << 2];
            float4 b = *(const float4*)&Bs[k][tx << 2];
            acc[0][0] += a.x * b.x; acc[0][1] += a.x * b.y; acc[0][2] += a.x * b.z; acc[0][3] += a.x * b.w;
            acc[1][0] += a.y * b.x; acc[1][1] += a.y * b.y; acc[1][2] += a.y * b.z; acc[1][3] += a.y * b.w;
            acc[2][0] += a.z * b.x; acc[2][1] += a.z * b.y; acc[2][2] += a.z * b.z; acc[2][3] += a.z * b.w;
            acc[3][0] += a.w * b.x; acc[3][1] += a.w * b.y; acc[3][2] += a.w * b.z; acc[3][3] += a.w * b.w;
        }
    }
    const int cn = n0 + (tx << 2);
    const float bb0 = bias[cn + 0], bb1 = bias[cn + 1], bb2 = bias[cn + 2], bb3 = bias[cn + 3];
#pragma unroll
    for (int i = 0; i < 4; ++i) {
        float4 o;
        o.x = acc[i][0] + bb0; o.y = acc[i][1] + bb1;
        o.z = acc[i][2] + bb2; o.w = acc[i][3] + bb3;
        *(float4*)(C + (size_t)(m0 + (ty << 2) + i) * N + cn) = o;
    }
}

// ------------------------------------------- per-channel sum / sumsq (BN stats)
__global__ __launch_bounds__(256) void stats_kernel(
    const float* __restrict__ y, float* __restrict__ ssum, float* __restrict__ ssq)
{
    const int c = threadIdx.x;
    const size_t base = (size_t)blockIdx.x * 128 * H_;
    float s = 0.0f, q = 0.0f;
    for (int r = 0; r < 128; ++r) {
        float v = y[base + (size_t)r * H_ + c];
        s += v;
        q += v * v;
    }
    atomicAdd(&ssum[c], s);
    atomicAdd(&ssq[c], q);
}

// ------------------------------------------- BN + ReLU in place on y[32768][256]
__global__ __launch_bounds__(256) void bn_relu_kernel(
    float* __restrict__ y, const float* __restrict__ ssum, const float* __restrict__ ssq,
    const float* __restrict__ g, const float* __restrict__ beta)
{
    __shared__ float sc[H_], sh[H_];
    const float invN = 1.0f / (float)ROWS_;
    const int t = threadIdx.x;
    {
        float mu  = ssum[t] * invN;
        float var = ssq[t] * invN - mu * mu;
        float s   = rsqrtf(var + 1e-3f) * g[t];
        sc[t] = s;
        sh[t] = beta[t] - mu * s;
    }
    __syncthreads();
    const int c0 = (t << 2) & (H_ - 1);
    const float s0 = sc[c0], s1 = sc[c0 + 1], s2 = sc[c0 + 2], s3 = sc[c0 + 3];
    const float h0 = sh[c0], h1 = sh[c0 + 1], h2 = sh[c0 + 2], h3 = sh[c0 + 3];
    float4* yp = (float4*)y;
    const size_t base = (size_t)blockIdx.x * 1024 + t;
#pragma unroll
    for (int j = 0; j < 4; ++j) {
        float4 v = yp[base + j * 256];
        v.x = fmaxf(v.x * s0 + h0, 0.0f);
        v.y = fmaxf(v.y * s1 + h1, 0.0f);
        v.z = fmaxf(v.z * s2 + h2, 0.0f);
        v.w = fmaxf(v.w * s3 + h3, 0.0f);
        yp[base + j * 256] = v;
    }
}

// ------------------------------------------- BN + ReLU + transpose to out[B,256,N2]
__global__ __launch_bounds__(256) void bn_out_kernel(
    const float* __restrict__ y, const float* __restrict__ ssum, const float* __restrict__ ssq,
    const float* __restrict__ g, const float* __restrict__ beta, float* __restrict__ out)
{
    __shared__ float tile[64][65];
    __shared__ float sc[64], sh[64];
    const float invN = 1.0f / (float)ROWS_;
    const int bid = blockIdx.x;
    const int b  = bid >> 8;         // 256 blocks per batch (64 ntiles * 4 otiles)
    const int nt = (bid >> 2) & 63;
    const int ot = bid & 3;
    const int t = threadIdx.x;
    if (t < 64) {
        int c = ot * 64 + t;
        float mu  = ssum[c] * invN;
        float var = ssq[c] * invN - mu * mu;
        float s   = rsqrtf(var + 1e-3f) * g[c];
        sc[t] = s;
        sh[t] = beta[c] - mu * s;
    }
    __syncthreads();
    const int n0 = nt * 64, o0 = ot * 64;
    const float* yb = y + ((size_t)b * N2_ + n0) * H_ + o0;
#pragma unroll
    for (int j = 0; j < 16; ++j) {
        int lin = j * 256 + t;
        int nl = lin >> 6, ol = lin & 63;
        float v = yb[(size_t)nl * H_ + ol];
        tile[nl][ol] = fmaxf(v * sc[ol] + sh[ol], 0.0f);
    }
    __syncthreads();
    float* ob = out + ((size_t)b * H_ + o0) * N2_ + n0;
#pragma unroll
    for (int j = 0; j < 16; ++j) {
        int lin = j * 256 + t;
        int ol = lin >> 6, nl = lin & 63;
        ob[(size_t)ol * N2_ + nl] = tile[nl][ol];
    }
}

// ----------------------------------------------------------------------------
extern "C" void kernel_launch(void* const* d_in, const int* in_sizes, int n_in,
                              void* d_out, int out_size, void* d_ws, size_t ws_size,
                              hipStream_t stream)
{
    (void)in_sizes; (void)n_in; (void)out_size; (void)ws_size;
    const float* points1   = (const float*)d_in[0];
    const float* points2   = (const float*)d_in[1];
    const float* features1 = (const float*)d_in[2];
    const float* features2 = (const float*)d_in[3];
    const float* skipf     = (const float*)d_in[4];
    const float* W1  = (const float*)d_in[5];
    const float* b1  = (const float*)d_in[6];
    const float* g1  = (const float*)d_in[7];
    const float* be1 = (const float*)d_in[8];
    const float* W2  = (const float*)d_in[9];
    const float* b2  = (const float*)d_in[10];
    const float* g2  = (const float*)d_in[11];
    const float* be2 = (const float*)d_in[12];
    float* out = (float*)d_out;

    char* ws = (char*)d_ws;
    float* s1  = (float*)(ws + 0);
    float* q1  = (float*)(ws + 1024);
    float* s2  = (float*)(ws + 2048);
    float* q2  = (float*)(ws + 3072);
    int*   ind = (int*)  (ws + 4096);                      //  98304 ints
    float* wgt = (float*)(ws + 397312);                    //  98304 floats
    float* x   = (float*)(ws + 790528);                    //  32768*448 floats (58.7 MB)
    float* y1  = (float*)(ws + 59510784);                  //  32768*256 floats (33.6 MB)
    float* y2  = x;                                        //  alias: x dead after gemm1

    hipMemsetAsync(ws, 0, 4096, stream);                   // zero BN stats (ws is poisoned)

    knn_kernel<<<dim3(512), dim3(256), 0, stream>>>(points1, points2, ind, wgt);
    build_x_kernel<<<dim3(ROWS_), dim3(448), 0, stream>>>(features1, features2, skipf, ind, wgt, x);

    gemm_nt<<<dim3(ROWS_ / 64, H_ / 64), dim3(256), 0, stream>>>(x, W1, b1, y1, ROWS_, H_, CT_);
    stats_kernel<<<dim3(256), dim3(256), 0, stream>>>(y1, s1, q1);
    bn_relu_kernel<<<dim3(2048), dim3(256), 0, stream>>>(y1, s1, q1, g1, be1);

    gemm_nt<<<dim3(ROWS_ / 64, H_ / 64), dim3(256), 0, stream>>>(y1, W2, b2, y2, ROWS_, H_, H_);
    stats_kernel<<<dim3(256), dim3(256), 0, stream>>>(y2, s2, q2);
    bn_out_kernel<<<dim3(2048), dim3(256), 0, stream>>>(y2, s2, q2, g2, be2, out);
}

// Round 3
// 287.139 us; speedup vs baseline: 2.4155x; 1.7741x over previous
//
#include <hip/hip_runtime.h>
#include <cstdint>
#include <cstddef>

#define B_    8
#define N1_   1024
#define N2_   4096
#define C1_   256
#define C2_   128
#define CS_   64
#define CT_   448
#define H_    256
#define ROWS_ (B_ * N2_)   // 32768

typedef __attribute__((ext_vector_type(8))) short bf16x8;
typedef __attribute__((ext_vector_type(4))) float f32x4;
typedef unsigned short ushort_t;
typedef unsigned int   uint_t;

__device__ __forceinline__ ushort_t f2bf(float f) {
    uint_t u = __float_as_uint(f);
    u = (u + 0x7fffu + ((u >> 16) & 1u)) >> 16;   // RNE
    return (ushort_t)u;
}
__device__ __forceinline__ float bf2f(ushort_t h) {
    return __uint_as_float(((uint_t)h) << 16);
}

// ---------------------------------------------------------------- KNN (K=3)
__global__ __launch_bounds__(256) void knn_kernel(
    const float* __restrict__ p1, const float* __restrict__ p2,
    int* __restrict__ ind, float* __restrict__ wout)
{
#pragma clang fp contract(off)
    __shared__ float4 cand[N1_];
    __shared__ float  pd[256][3];
    __shared__ int    pi[256][3];
    const int t = threadIdx.x;
    const int b = blockIdx.x >> 6;
    const int qbase = (blockIdx.x & 63) * 64;
    const float* pb1 = p1 + (size_t)b * 3 * N1_;
    for (int i = t; i < N1_; i += 256) {
        float X = pb1[i], Y = pb1[N1_ + i], Z = pb1[2 * N1_ + i];
        cand[i] = make_float4(X, Y, Z, (X * X + Y * Y) + Z * Z);
    }
    const int n = qbase + (t & 63);
    const int split = t >> 6;
    const float* pb2 = p2 + (size_t)b * 3 * N2_;
    const float qx = pb2[n], qy = pb2[N2_ + n], qz = pb2[2 * N2_ + n];
    const float s2 = (qx * qx + qy * qy) + qz * qz;
    __syncthreads();
    float d0 = 3.0e38f, d1 = 3.0e38f, d2v = 3.0e38f;
    int   i0 = 0, i1 = 0, i2 = 0;
    const int ibeg = split * (N1_ / 4);
    const int iend = ibeg + (N1_ / 4);
    for (int i = ibeg; i < iend; ++i) {
        float4 c = cand[i];
        float dot = (qx * c.x + qy * c.y) + qz * c.z;
        float dd  = (s2 + c.w) - 2.0f * dot;
        float d   = sqrtf(fmaxf(dd, 0.0f));
        if (d < d0)       { d2v = d1; i2 = i1; d1 = d0; i1 = i0; d0 = d; i0 = i; }
        else if (d < d1)  { d2v = d1; i2 = i1; d1 = d;  i1 = i; }
        else if (d < d2v) { d2v = d;  i2 = i; }
    }
    pd[t][0] = d0; pd[t][1] = d1; pd[t][2] = d2v;
    pi[t][0] = i0; pi[t][1] = i1; pi[t][2] = i2;
    __syncthreads();
    if (t < 64) {
        float e0 = 3.0e38f, e1 = 3.0e38f, e2 = 3.0e38f;
        int   j0 = 0, j1 = 0, j2 = 0;
#pragma unroll
        for (int s = 0; s < 4; ++s) {
            const int src = s * 64 + t;
#pragma unroll
            for (int r = 0; r < 3; ++r) {
                float d = pd[src][r];
                int   i = pi[src][r];
                if (d < e0)      { e2 = e1; j2 = j1; e1 = e0; j1 = j0; e0 = d; j0 = i; }
                else if (d < e1) { e2 = e1; j2 = j1; e1 = d;  j1 = i; }
                else if (d < e2) { e2 = d;  j2 = i; }
            }
        }
        float inv0 = 1.0f / (e0 + 1e-10f);
        float inv1 = 1.0f / (e1 + 1e-10f);
        float inv2 = 1.0f / (e2 + 1e-10f);
        float s = (inv0 + inv1) + inv2;
        const size_t row = (size_t)b * N2_ + qbase + t;
        wout[row * 3 + 0] = inv0 / s;
        wout[row * 3 + 1] = inv1 / s;
        wout[row * 3 + 2] = inv2 / s;
        ind[row * 3 + 0] = j0;
        ind[row * 3 + 1] = j1;
        ind[row * 3 + 2] = j2;
    }
}

// ------------------------------- transpose f1 [B,C1,N1] f32 -> f1t [B,N1,C1] bf16
__global__ __launch_bounds__(256) void transpose_f1(
    const float* __restrict__ f1, ushort_t* __restrict__ f1t)
{
    __shared__ float tile[64][65];
    const int t = threadIdx.x;
    const int bid = blockIdx.x;            // 8b x 4ct x 16nt = 512
    const int b  = bid >> 6;
    const int ct = (bid >> 4) & 3;
    const int nt = bid & 15;
    const int c0 = ct * 64, n0 = nt * 64;
    const float* src = f1 + ((size_t)b * C1_ + c0) * N1_ + n0;
#pragma unroll
    for (int j = 0; j < 16; ++j) {
        int lin = j * 256 + t;
        int ci = lin >> 6, nj = lin & 63;
        tile[ci][nj] = src[(size_t)ci * N1_ + nj];
    }
    __syncthreads();
    ushort_t* dst = f1t + ((size_t)b * N1_ + n0) * C1_ + c0;
#pragma unroll
    for (int j = 0; j < 8; ++j) {
        int lin = j * 256 + t;
        int ni = lin >> 5, cjp = (lin & 31) * 2;
        uint_t u = (uint_t)f2bf(tile[cjp][ni]) | ((uint_t)f2bf(tile[cjp + 1][ni]) << 16);
        *(uint_t*)&dst[(size_t)ni * C1_ + cjp] = u;
    }
}

// ------------------------------- f2/skip transpose directly into x_bf16 tail cols
__global__ __launch_bounds__(256) void transpose_f2s(
    const float* __restrict__ f2, const float* __restrict__ fs, ushort_t* __restrict__ x)
{
    __shared__ float tile[64][65];
    const int t = threadIdx.x;
    const int bid = blockIdx.x;            // 8b x 3ct x 64nt = 1536
    const int b   = bid / 192;
    const int rem = bid - b * 192;
    const int ct  = rem >> 6;
    const int nt  = rem & 63;
    const float* src;
    int coff;
    if (ct < 2) { src = f2 + ((size_t)b * C2_ + ct * 64) * N2_; coff = C1_ + ct * 64; }
    else        { src = fs + (size_t)b * CS_ * N2_;             coff = C1_ + C2_; }
    const int n0 = nt * 64;
#pragma unroll
    for (int j = 0; j < 16; ++j) {
        int lin = j * 256 + t;
        int ci = lin >> 6, nj = lin & 63;
        tile[ci][nj] = src[(size_t)ci * N2_ + n0 + nj];
    }
    __syncthreads();
#pragma unroll
    for (int j = 0; j < 8; ++j) {
        int lin = j * 256 + t;
        int ni = lin >> 5, cjp = (lin & 31) * 2;
        uint_t u = (uint_t)f2bf(tile[cjp][ni]) | ((uint_t)f2bf(tile[cjp + 1][ni]) << 16);
        *(uint_t*)&x[((size_t)b * N2_ + n0 + ni) * CT_ + coff + cjp] = u;
    }
}

// ------------------------------- gather+interp -> x_bf16[:, 0:256]
__global__ __launch_bounds__(256) void gather_x(
    const ushort_t* __restrict__ f1t, const int* __restrict__ ind,
    const float* __restrict__ w, ushort_t* __restrict__ x)
{
    const int t = threadIdx.x;
    const int row = blockIdx.x * 8 + (t >> 5);
    const int b = row >> 12;
    const int cg = (t & 31) * 8;
    const int*   ip = ind + (size_t)row * 3;
    const float* wp = w   + (size_t)row * 3;
    const int i0 = ip[0], i1 = ip[1], i2 = ip[2];
    const float w0 = wp[0], w1 = wp[1], w2 = wp[2];
    const ushort_t* base = f1t + (size_t)b * N1_ * C1_;
    uint4 va = *(const uint4*)(base + (size_t)i0 * C1_ + cg);
    uint4 vb = *(const uint4*)(base + (size_t)i1 * C1_ + cg);
    uint4 vc = *(const uint4*)(base + (size_t)i2 * C1_ + cg);
    const uint_t* pa = (const uint_t*)&va;
    const uint_t* pb = (const uint_t*)&vb;
    const uint_t* pc = (const uint_t*)&vc;
    uint_t out[4];
#pragma unroll
    for (int e = 0; e < 4; ++e) {
        float lo = w0 * bf2f((ushort_t)(pa[e] & 0xffff))
                 + w1 * bf2f((ushort_t)(pb[e] & 0xffff))
                 + w2 * bf2f((ushort_t)(pc[e] & 0xffff));
        float hi = w0 * bf2f((ushort_t)(pa[e] >> 16))
                 + w1 * bf2f((ushort_t)(pb[e] >> 16))
                 + w2 * bf2f((ushort_t)(pc[e] >> 16));
        out[e] = (uint_t)f2bf(lo) | ((uint_t)f2bf(hi) << 16);
    }
    *(uint4*)&x[(size_t)row * CT_ + cg] = *(uint4*)out;
}

// ------------------------------- convert W1/W2 to bf16
__global__ __launch_bounds__(256) void convert_w(
    const float* __restrict__ W1, const float* __restrict__ W2,
    ushort_t* __restrict__ W1b, ushort_t* __restrict__ W2b)
{
    const int i = blockIdx.x * 256 + threadIdx.x;
    if (i < H_ * CT_) W1b[i] = f2bf(W1[i]);
    if (i < H_ * H_)  W2b[i] = f2bf(W2[i]);
}

// ------------------------------- bf16 MFMA GEMM: C[m,n] = A[m,:]·Bw[n,:] + bias[n]
// 128x128 tile, BK=32, 4 waves each 64x64 (4x4 frags of 16x16x32)
__global__ __launch_bounds__(256) void gemm_bf16(
    const ushort_t* __restrict__ A, const ushort_t* __restrict__ Bw,
    const float* __restrict__ bias, float* __restrict__ C, int N, int K)
{
    __shared__ __align__(16) ushort_t As[128 * 40];
    __shared__ __align__(16) ushort_t Bs[128 * 40];
    const int t = threadIdx.x;
    const int m0 = blockIdx.x * 128;
    const int n0 = blockIdx.y * 128;
    const int lane = t & 63;
    const int wv = t >> 6;
    const int wr = wv >> 1;            // wave row 0..1
    const int wc = wv & 1;             // wave col 0..1
    const int lm = lane & 15;
    const int lq = lane >> 4;
    f32x4 acc[4][4];
#pragma unroll
    for (int i = 0; i < 4; ++i)
#pragma unroll
        for (int j = 0; j < 4; ++j)
            acc[i][j] = (f32x4){0.f, 0.f, 0.f, 0.f};

    for (int k0 = 0; k0 < K; k0 += 32) {
        uint4 av[2], bv[2];
#pragma unroll
        for (int q = 0; q < 2; ++q) {
            int idx = q * 256 + t;
            int row = idx >> 2, kc = idx & 3;
            av[q] = *(const uint4*)(A  + (size_t)(m0 + row) * K + k0 + kc * 8);
            bv[q] = *(const uint4*)(Bw + (size_t)(n0 + row) * K + k0 + kc * 8);
        }
        __syncthreads();
#pragma unroll
        for (int q = 0; q < 2; ++q) {
            int idx = q * 256 + t;
            int row = idx >> 2, kc = idx & 3;
            *(uint4*)&As[row * 40 + kc * 8] = av[q];
            *(uint4*)&Bs[row * 40 + kc * 8] = bv[q];
        }
        __syncthreads();
        bf16x8 af[4], bfr[4];
#pragma unroll
        for (int i = 0; i < 4; ++i)
            af[i] = *(const bf16x8*)&As[(wr * 64 + i * 16 + lm) * 40 + lq * 8];
#pragma unroll
        for (int j = 0; j < 4; ++j)
            bfr[j] = *(const bf16x8*)&Bs[(wc * 64 + j * 16 + lm) * 40 + lq * 8];
#pragma unroll
        for (int i = 0; i < 4; ++i)
#pragma unroll
            for (int j = 0; j < 4; ++j)
                acc[i][j] = __builtin_amdgcn_mfma_f32_16x16x32_bf16(af[i], bfr[j], acc[i][j], 0, 0, 0);
    }
#pragma unroll
    for (int j = 0; j < 4; ++j) {
        const int gn = n0 + wc * 64 + j * 16 + lm;
        const float bb = bias[gn];
#pragma unroll
        for (int i = 0; i < 4; ++i) {
            const int gm = m0 + wr * 64 + i * 16 + lq * 4;
            f32x4 v = acc[i][j];
#pragma unroll
            for (int r = 0; r < 4; ++r)
                C[(size_t)(gm + r) * N + gn] = v[r] + bb;
        }
    }
}

// ------------------------------- per-channel sum / sumsq (BN stats)
__global__ __launch_bounds__(256) void stats_kernel(
    const float* __restrict__ y, float* __restrict__ ssum, float* __restrict__ ssq)
{
    const int c = threadIdx.x;
    const size_t base = (size_t)blockIdx.x * 128 * H_;
    float s = 0.0f, q = 0.0f;
    for (int r = 0; r < 128; ++r) {
        float v = y[base + (size_t)r * H_ + c];
        s += v;
        q += v * v;
    }
    atomicAdd(&ssum[c], s);
    atomicAdd(&ssq[c], q);
}

// ------------------------------- BN + ReLU, fp32 y -> bf16 yb
__global__ __launch_bounds__(256) void bn_relu_bf16(
    const float* __restrict__ y, const float* __restrict__ ssum, const float* __restrict__ ssq,
    const float* __restrict__ g, const float* __restrict__ beta, ushort_t* __restrict__ yb)
{
    __shared__ float sc[H_], sh[H_];
    const float invN = 1.0f / (float)ROWS_;
    const int t = threadIdx.x;
    {
        float mu  = ssum[t] * invN;
        float var = ssq[t] * invN - mu * mu;
        float s   = rsqrtf(var + 1e-3f) * g[t];
        sc[t] = s;
        sh[t] = beta[t] - mu * s;
    }
    __syncthreads();
    const int c0 = (t << 2) & (H_ - 1);
    const float s0 = sc[c0], s1 = sc[c0 + 1], s2 = sc[c0 + 2], s3 = sc[c0 + 3];
    const float h0 = sh[c0], h1 = sh[c0 + 1], h2 = sh[c0 + 2], h3 = sh[c0 + 3];
    const float4* yp = (const float4*)y;
    const size_t base = (size_t)blockIdx.x * 1024 + t;
#pragma unroll
    for (int j = 0; j < 4; ++j) {
        float4 v = yp[base + j * 256];
        uint_t lo = (uint_t)f2bf(fmaxf(v.x * s0 + h0, 0.0f)) |
                    ((uint_t)f2bf(fmaxf(v.y * s1 + h1, 0.0f)) << 16);
        uint_t hi = (uint_t)f2bf(fmaxf(v.z * s2 + h2, 0.0f)) |
                    ((uint_t)f2bf(fmaxf(v.w * s3 + h3, 0.0f)) << 16);
        uint2 u = make_uint2(lo, hi);
        *(uint2*)&yb[(base + j * 256) * 4] = u;
    }
}

// ------------------------------- BN + ReLU + transpose to out[B,256,N2]
__global__ __launch_bounds__(256) void bn_out_kernel(
    const float* __restrict__ y, const float* __restrict__ ssum, const float* __restrict__ ssq,
    const float* __restrict__ g, const float* __restrict__ beta, float* __restrict__ out)
{
    __shared__ float tile[64][65];
    __shared__ float sc[64], sh[64];
    const float invN = 1.0f / (float)ROWS_;
    const int bid = blockIdx.x;
    const int b  = bid >> 8;
    const int nt = (bid >> 2) & 63;
    const int ot = bid & 3;
    const int t = threadIdx.x;
    if (t < 64) {
        int c = ot * 64 + t;
        float mu  = ssum[c] * invN;
        float var = ssq[c] * invN - mu * mu;
        float s   = rsqrtf(var + 1e-3f) * g[c];
        sc[t] = s;
        sh[t] = beta[c] - mu * s;
    }
    __syncthreads();
    const int n0 = nt * 64, o0 = ot * 64;
    const float* yb = y + ((size_t)b * N2_ + n0) * H_ + o0;
#pragma unroll
    for (int j = 0; j < 16; ++j) {
        int lin = j * 256 + t;
        int nl = lin >> 6, ol = lin & 63;
        float v = yb[(size_t)nl * H_ + ol];
        tile[nl][ol] = fmaxf(v * sc[ol] + sh[ol], 0.0f);
    }
    __syncthreads();
    float* ob = out + ((size_t)b * H_ + o0) * N2_ + n0;
#pragma unroll
    for (int j = 0; j < 16; ++j) {
        int lin = j * 256 + t;
        int ol = lin >> 6, nl = lin & 63;
        ob[(size_t)ol * N2_ + nl] = tile[nl][ol];
    }
}

// ----------------------------------------------------------------------------
extern "C" void kernel_launch(void* const* d_in, const int* in_sizes, int n_in,
                              void* d_out, int out_size, void* d_ws, size_t ws_size,
                              hipStream_t stream)
{
    (void)in_sizes; (void)n_in; (void)out_size; (void)ws_size;
    const float* points1   = (const float*)d_in[0];
    const float* points2   = (const float*)d_in[1];
    const float* features1 = (const float*)d_in[2];
    const float* features2 = (const float*)d_in[3];
    const float* skipf     = (const float*)d_in[4];
    const float* W1  = (const float*)d_in[5];
    const float* b1  = (const float*)d_in[6];
    const float* g1  = (const float*)d_in[7];
    const float* be1 = (const float*)d_in[8];
    const float* W2  = (const float*)d_in[9];
    const float* b2  = (const float*)d_in[10];
    const float* g2  = (const float*)d_in[11];
    const float* be2 = (const float*)d_in[12];
    float* out = (float*)d_out;

    char* ws = (char*)d_ws;
    float*    s1  = (float*)(ws + 0);
    float*    q1  = (float*)(ws + 1024);
    float*    s2  = (float*)(ws + 2048);
    float*    q2  = (float*)(ws + 3072);
    int*      ind = (int*)(ws + 4096);                 // 393216 B
    float*    wgt = (float*)(ws + 397312);             // 393216 B
    ushort_t* x   = (ushort_t*)(ws + 790528);          // 29,360,128 B (bf16 32768x448)
    float*    y1  = (float*)(ws + 30150656);           // 33,554,432 B (fp32 32768x256)
    ushort_t* W1b = (ushort_t*)(ws + 63705088);        // 229,376 B
    ushort_t* W2b = (ushort_t*)(ws + 63934464);        // 131,072 B
    ushort_t* f1t = (ushort_t*)(ws + 64065536);        // 4,194,304 B (bf16 8x1024x256)
    ushort_t* y1b = x;                                 // alias: x dead after gemm1
    float*    y2  = y1;                                // alias: y1 dead after bn_relu

    hipMemsetAsync(ws, 0, 4096, stream);               // zero BN stats

    knn_kernel<<<dim3(512), dim3(256), 0, stream>>>(points1, points2, ind, wgt);
    transpose_f1<<<dim3(512), dim3(256), 0, stream>>>(features1, f1t);
    convert_w<<<dim3(448), dim3(256), 0, stream>>>(W1, W2, W1b, W2b);
    gather_x<<<dim3(4096), dim3(256), 0, stream>>>(f1t, ind, wgt, x);
    transpose_f2s<<<dim3(1536), dim3(256), 0, stream>>>(features2, skipf, x);

    gemm_bf16<<<dim3(ROWS_ / 128, 2), dim3(256), 0, stream>>>(x, W1b, b1, y1, H_, CT_);
    stats_kernel<<<dim3(256), dim3(256), 0, stream>>>(y1, s1, q1);
    bn_relu_bf16<<<dim3(2048), dim3(256), 0, stream>>>(y1, s1, q1, g1, be1, y1b);

    gemm_bf16<<<dim3(ROWS_ / 128, 2), dim3(256), 0, stream>>>(y1b, W2b, b2, y2, H_, H_);
    stats_kernel<<<dim3(256), dim3(256), 0, stream>>>(y2, s2, q2);
    bn_out_kernel<<<dim3(2048), dim3(256), 0, stream>>>(y2, s2, q2, g2, be2, out);
}

// Round 4
// 259.434 us; speedup vs baseline: 2.6735x; 1.1068x over previous
//
#include <hip/hip_runtime.h>
#include <cstdint>
#include <cstddef>

#define B_    8
#define N1_   1024
#define N2_   4096
#define C1_   256
#define C2_   128
#define CS_   64
#define CT_   448
#define H_    256
#define ROWS_ (B_ * N2_)   // 32768

typedef __attribute__((ext_vector_type(8))) short bf16x8;
typedef __attribute__((ext_vector_type(4))) float f32x4;
typedef unsigned short ushort_t;
typedef unsigned int   uint_t;

__device__ __forceinline__ ushort_t f2bf(float f) {
    uint_t u = __float_as_uint(f);
    u = (u + 0x7fffu + ((u >> 16) & 1u)) >> 16;   // RNE
    return (ushort_t)u;
}
__device__ __forceinline__ float bf2f(ushort_t h) {
    return __uint_as_float(((uint_t)h) << 16);
}

// ---------------------------------------------------------------- KNN (K=3)
// 2048 blocks x 256 threads: 16 queries x 16 index-ordered splits of 64 cands.
// Strict < on sqrt'd distance everywhere -> top_k lowest-index tie-break kept.
__global__ __launch_bounds__(256) void knn_kernel(
    const float* __restrict__ p1, const float* __restrict__ p2,
    int* __restrict__ ind, float* __restrict__ wout)
{
#pragma clang fp contract(off)
    __shared__ float4 cand[N1_];          // 16 KB
    __shared__ float  pd[256][3];
    __shared__ int    pi[256][3];
    __shared__ float  pd2[64][3];
    __shared__ int    pi2[64][3];
    const int t = threadIdx.x;
    const int b  = blockIdx.x >> 8;              // 256 blocks per batch
    const int qb = (blockIdx.x & 255) * 16;      // 16 queries per block
    const float* pb1 = p1 + (size_t)b * 3 * N1_;
    for (int i = t; i < N1_; i += 256) {
        float X = pb1[i], Y = pb1[N1_ + i], Z = pb1[2 * N1_ + i];
        cand[i] = make_float4(X, Y, Z, (X * X + Y * Y) + Z * Z);
    }
    const int q = t & 15, split = t >> 4;
    const int n = qb + q;
    const float* pb2 = p2 + (size_t)b * 3 * N2_;
    const float qx = pb2[n], qy = pb2[N2_ + n], qz = pb2[2 * N2_ + n];
    const float s2 = (qx * qx + qy * qy) + qz * qz;
    __syncthreads();
    float d0 = 3.0e38f, d1 = 3.0e38f, d2v = 3.0e38f;
    int   i0 = 0, i1 = 0, i2 = 0;
    const int ibeg = split * 64;
    for (int i = ibeg; i < ibeg + 64; ++i) {
        float4 c = cand[i];
        float dot = (qx * c.x + qy * c.y) + qz * c.z;
        float dd  = (s2 + c.w) - 2.0f * dot;
        float d   = sqrtf(fmaxf(dd, 0.0f));
        if (d < d0)       { d2v = d1; i2 = i1; d1 = d0; i1 = i0; d0 = d; i0 = i; }
        else if (d < d1)  { d2v = d1; i2 = i1; d1 = d;  i1 = i; }
        else if (d < d2v) { d2v = d;  i2 = i; }
    }
    pd[t][0] = d0; pd[t][1] = d1; pd[t][2] = d2v;
    pi[t][0] = i0; pi[t][1] = i1; pi[t][2] = i2;
    __syncthreads();
    if (t < 64) {                                // stage A: 4 splits -> 1 list
        const int qq = t & 15, g = t >> 4;
        float e0 = 3.0e38f, e1 = 3.0e38f, e2 = 3.0e38f;
        int   j0 = 0, j1 = 0, j2 = 0;
#pragma unroll
        for (int s = 0; s < 4; ++s) {
            const int src = (g * 4 + s) * 16 + qq;
#pragma unroll
            for (int r = 0; r < 3; ++r) {
                float d = pd[src][r];
                int   i = pi[src][r];
                if (d < e0)      { e2 = e1; j2 = j1; e1 = e0; j1 = j0; e0 = d; j0 = i; }
                else if (d < e1) { e2 = e1; j2 = j1; e1 = d;  j1 = i; }
                else if (d < e2) { e2 = d;  j2 = i; }
            }
        }
        pd2[t][0] = e0; pd2[t][1] = e1; pd2[t][2] = e2;
        pi2[t][0] = j0; pi2[t][1] = j1; pi2[t][2] = j2;
    }
    __syncthreads();
    if (t < 16) {                                // stage B: 4 groups -> final
        float e0 = 3.0e38f, e1 = 3.0e38f, e2 = 3.0e38f;
        int   j0 = 0, j1 = 0, j2 = 0;
#pragma unroll
        for (int g = 0; g < 4; ++g) {
            const int src = g * 16 + t;
#pragma unroll
            for (int r = 0; r < 3; ++r) {
                float d = pd2[src][r];
                int   i = pi2[src][r];
                if (d < e0)      { e2 = e1; j2 = j1; e1 = e0; j1 = j0; e0 = d; j0 = i; }
                else if (d < e1) { e2 = e1; j2 = j1; e1 = d;  j1 = i; }
                else if (d < e2) { e2 = d;  j2 = i; }
            }
        }
        float inv0 = 1.0f / (e0 + 1e-10f);
        float inv1 = 1.0f / (e1 + 1e-10f);
        float inv2 = 1.0f / (e2 + 1e-10f);
        float s = (inv0 + inv1) + inv2;
        const size_t row = (size_t)b * N2_ + qb + t;
        wout[row * 3 + 0] = inv0 / s;
        wout[row * 3 + 1] = inv1 / s;
        wout[row * 3 + 2] = inv2 / s;
        ind[row * 3 + 0] = j0;
        ind[row * 3 + 1] = j1;
        ind[row * 3 + 2] = j2;
    }
}

// ------------------------------- transpose f1 [B,C1,N1] f32 -> f1t [B,N1,C1] bf16
__global__ __launch_bounds__(256) void transpose_f1(
    const float* __restrict__ f1, ushort_t* __restrict__ f1t)
{
    __shared__ float tile[64][65];
    const int t = threadIdx.x;
    const int bid = blockIdx.x;            // 8b x 4ct x 16nt = 512
    const int b  = bid >> 6;
    const int ct = (bid >> 4) & 3;
    const int nt = bid & 15;
    const int c0 = ct * 64, n0 = nt * 64;
    const float* src = f1 + ((size_t)b * C1_ + c0) * N1_ + n0;
#pragma unroll
    for (int j = 0; j < 16; ++j) {
        int lin = j * 256 + t;
        int ci = lin >> 6, nj = lin & 63;
        tile[ci][nj] = src[(size_t)ci * N1_ + nj];
    }
    __syncthreads();
    ushort_t* dst = f1t + ((size_t)b * N1_ + n0) * C1_ + c0;
#pragma unroll
    for (int j = 0; j < 8; ++j) {
        int lin = j * 256 + t;
        int ni = lin >> 5, cjp = (lin & 31) * 2;
        uint_t u = (uint_t)f2bf(tile[cjp][ni]) | ((uint_t)f2bf(tile[cjp + 1][ni]) << 16);
        *(uint_t*)&dst[(size_t)ni * C1_ + cjp] = u;
    }
}

// ------------------------------- f2/skip transpose directly into x_bf16 tail cols
__global__ __launch_bounds__(256) void transpose_f2s(
    const float* __restrict__ f2, const float* __restrict__ fs, ushort_t* __restrict__ x)
{
    __shared__ float tile[64][65];
    const int t = threadIdx.x;
    const int bid = blockIdx.x;            // 8b x 3ct x 64nt = 1536
    const int b   = bid / 192;
    const int rem = bid - b * 192;
    const int ct  = rem >> 6;
    const int nt  = rem & 63;
    const float* src;
    int coff;
    if (ct < 2) { src = f2 + ((size_t)b * C2_ + ct * 64) * N2_; coff = C1_ + ct * 64; }
    else        { src = fs + (size_t)b * CS_ * N2_;             coff = C1_ + C2_; }
    const int n0 = nt * 64;
#pragma unroll
    for (int j = 0; j < 16; ++j) {
        int lin = j * 256 + t;
        int ci = lin >> 6, nj = lin & 63;
        tile[ci][nj] = src[(size_t)ci * N2_ + n0 + nj];
    }
    __syncthreads();
#pragma unroll
    for (int j = 0; j < 8; ++j) {
        int lin = j * 256 + t;
        int ni = lin >> 5, cjp = (lin & 31) * 2;
        uint_t u = (uint_t)f2bf(tile[cjp][ni]) | ((uint_t)f2bf(tile[cjp + 1][ni]) << 16);
        *(uint_t*)&x[((size_t)b * N2_ + n0 + ni) * CT_ + coff + cjp] = u;
    }
}

// ------------------------------- gather+interp -> x_bf16[:, 0:256]
__global__ __launch_bounds__(256) void gather_x(
    const ushort_t* __restrict__ f1t, const int* __restrict__ ind,
    const float* __restrict__ w, ushort_t* __restrict__ x)
{
    const int t = threadIdx.x;
    const int row = blockIdx.x * 8 + (t >> 5);
    const int b = row >> 12;
    const int cg = (t & 31) * 8;
    const int*   ip = ind + (size_t)row * 3;
    const float* wp = w   + (size_t)row * 3;
    const int i0 = ip[0], i1 = ip[1], i2 = ip[2];
    const float w0 = wp[0], w1 = wp[1], w2 = wp[2];
    const ushort_t* base = f1t + (size_t)b * N1_ * C1_;
    uint4 va = *(const uint4*)(base + (size_t)i0 * C1_ + cg);
    uint4 vb = *(const uint4*)(base + (size_t)i1 * C1_ + cg);
    uint4 vc = *(const uint4*)(base + (size_t)i2 * C1_ + cg);
    const uint_t* pa = (const uint_t*)&va;
    const uint_t* pb = (const uint_t*)&vb;
    const uint_t* pc = (const uint_t*)&vc;
    uint_t out[4];
#pragma unroll
    for (int e = 0; e < 4; ++e) {
        float lo = w0 * bf2f((ushort_t)(pa[e] & 0xffff))
                 + w1 * bf2f((ushort_t)(pb[e] & 0xffff))
                 + w2 * bf2f((ushort_t)(pc[e] & 0xffff));
        float hi = w0 * bf2f((ushort_t)(pa[e] >> 16))
                 + w1 * bf2f((ushort_t)(pb[e] >> 16))
                 + w2 * bf2f((ushort_t)(pc[e] >> 16));
        out[e] = (uint_t)f2bf(lo) | ((uint_t)f2bf(hi) << 16);
    }
    *(uint4*)&x[(size_t)row * CT_ + cg] = *(uint4*)out;
}

// ------------------------------- convert W1/W2 to bf16
__global__ __launch_bounds__(256) void convert_w(
    const float* __restrict__ W1, const float* __restrict__ W2,
    ushort_t* __restrict__ W1b, ushort_t* __restrict__ W2b)
{
    const int i = blockIdx.x * 256 + threadIdx.x;
    if (i < H_ * CT_) W1b[i] = f2bf(W1[i]);
    if (i < H_ * H_)  W2b[i] = f2bf(W2[i]);
}

// ------------------------------- GEMM1: y1[m,n] = x[m,:]·W1b[n,:] + b1[n], fp32 out
// + fused per-channel sum/sumsq atomics (BN1 stats). 128x128 tile, BK=32.
__global__ __launch_bounds__(256) void gemm1_bf16(
    const ushort_t* __restrict__ A, const ushort_t* __restrict__ Bw,
    const float* __restrict__ bias, float* __restrict__ C,
    float* __restrict__ ssum, float* __restrict__ ssq)
{
    __shared__ __align__(16) ushort_t As[128 * 40];
    __shared__ __align__(16) ushort_t Bs[128 * 40];
    const int t = threadIdx.x;
    const int m0 = blockIdx.x * 128;
    const int n0 = blockIdx.y * 128;
    const int lane = t & 63;
    const int wv = t >> 6;
    const int wr = wv >> 1, wc = wv & 1;
    const int lm = lane & 15, lq = lane >> 4;
    f32x4 acc[4][4];
#pragma unroll
    for (int i = 0; i < 4; ++i)
#pragma unroll
        for (int j = 0; j < 4; ++j)
            acc[i][j] = (f32x4){0.f, 0.f, 0.f, 0.f};

    for (int k0 = 0; k0 < CT_; k0 += 32) {
        uint4 av[2], bv[2];
#pragma unroll
        for (int qq = 0; qq < 2; ++qq) {
            int idx = qq * 256 + t;
            int row = idx >> 2, kc = idx & 3;
            av[qq] = *(const uint4*)(A  + (size_t)(m0 + row) * CT_ + k0 + kc * 8);
            bv[qq] = *(const uint4*)(Bw + (size_t)(n0 + row) * CT_ + k0 + kc * 8);
        }
        __syncthreads();
#pragma unroll
        for (int qq = 0; qq < 2; ++qq) {
            int idx = qq * 256 + t;
            int row = idx >> 2, kc = idx & 3;
            *(uint4*)&As[row * 40 + kc * 8] = av[qq];
            *(uint4*)&Bs[row * 40 + kc * 8] = bv[qq];
        }
        __syncthreads();
        bf16x8 af[4], bfr[4];
#pragma unroll
        for (int i = 0; i < 4; ++i)
            af[i] = *(const bf16x8*)&As[(wr * 64 + i * 16 + lm) * 40 + lq * 8];
#pragma unroll
        for (int j = 0; j < 4; ++j)
            bfr[j] = *(const bf16x8*)&Bs[(wc * 64 + j * 16 + lm) * 40 + lq * 8];
#pragma unroll
        for (int i = 0; i < 4; ++i)
#pragma unroll
            for (int j = 0; j < 4; ++j)
                acc[i][j] = __builtin_amdgcn_mfma_f32_16x16x32_bf16(af[i], bfr[j], acc[i][j], 0, 0, 0);
    }
#pragma unroll
    for (int j = 0; j < 4; ++j) {
        const int gn = n0 + wc * 64 + j * 16 + lm;
        const float bb = bias[gn];
        float ps = 0.0f, pq = 0.0f;
#pragma unroll
        for (int i = 0; i < 4; ++i) {
            const int gm = m0 + wr * 64 + i * 16 + lq * 4;
            f32x4 v = acc[i][j];
#pragma unroll
            for (int r = 0; r < 4; ++r) {
                float val = v[r] + bb;
                C[(size_t)(gm + r) * H_ + gn] = val;
                ps += val;
                pq += val * val;
            }
        }
        ps += __shfl_xor(ps, 16); pq += __shfl_xor(pq, 16);
        ps += __shfl_xor(ps, 32); pq += __shfl_xor(pq, 32);
        if (lane < 16) {
            atomicAdd(&ssum[gn], ps);
            atomicAdd(&ssq[gn], pq);
        }
    }
}

// ------------------------------- GEMM2: A = BN1(y1 fp32)+ReLU -> bf16 in staging.
// Out: y2 bf16 + fused BN2 stats atomics (stats on fp32 accumulators).
__global__ __launch_bounds__(256) void gemm2_fused(
    const float* __restrict__ A, const ushort_t* __restrict__ Bw,
    const float* __restrict__ bias,
    const float* __restrict__ s1, const float* __restrict__ q1,
    const float* __restrict__ g1, const float* __restrict__ be1,
    ushort_t* __restrict__ C, float* __restrict__ ssum, float* __restrict__ ssq)
{
    __shared__ __align__(16) ushort_t As[128 * 40];
    __shared__ __align__(16) ushort_t Bs[128 * 40];
    __shared__ float sc[H_], sh[H_];
    const int t = threadIdx.x;
    const int m0 = blockIdx.x * 128;
    const int n0 = blockIdx.y * 128;
    const int lane = t & 63;
    const int wv = t >> 6;
    const int wr = wv >> 1, wc = wv & 1;
    const int lm = lane & 15, lq = lane >> 4;
    {
        const float invN = 1.0f / (float)ROWS_;
        float mu  = s1[t] * invN;
        float var = q1[t] * invN - mu * mu;
        float s   = rsqrtf(var + 1e-3f) * g1[t];
        sc[t] = s;
        sh[t] = be1[t] - mu * s;
    }
    f32x4 acc[4][4];
#pragma unroll
    for (int i = 0; i < 4; ++i)
#pragma unroll
        for (int j = 0; j < 4; ++j)
            acc[i][j] = (f32x4){0.f, 0.f, 0.f, 0.f};
    __syncthreads();

    const int arow = t >> 1, ahalf = (t & 1) * 16;
    for (int k0 = 0; k0 < H_; k0 += 32) {
        const float* asrc = A + (size_t)(m0 + arow) * H_ + k0 + ahalf;
        float4 a0 = *(const float4*)(asrc + 0);
        float4 a1 = *(const float4*)(asrc + 4);
        float4 a2 = *(const float4*)(asrc + 8);
        float4 a3 = *(const float4*)(asrc + 12);
        uint4 bv[2];
#pragma unroll
        for (int qq = 0; qq < 2; ++qq) {
            int idx = qq * 256 + t;
            int row = idx >> 2, kc = idx & 3;
            bv[qq] = *(const uint4*)(Bw + (size_t)(n0 + row) * H_ + k0 + kc * 8);
        }
        __syncthreads();
        {
            float f[16] = {a0.x, a0.y, a0.z, a0.w, a1.x, a1.y, a1.z, a1.w,
                           a2.x, a2.y, a2.z, a2.w, a3.x, a3.y, a3.z, a3.w};
            const int cb = k0 + ahalf;
            uint_t u[8];
#pragma unroll
            for (int e = 0; e < 8; ++e) {
                float lo = fmaxf(f[2 * e]     * sc[cb + 2 * e]     + sh[cb + 2 * e],     0.0f);
                float hi = fmaxf(f[2 * e + 1] * sc[cb + 2 * e + 1] + sh[cb + 2 * e + 1], 0.0f);
                u[e] = (uint_t)f2bf(lo) | ((uint_t)f2bf(hi) << 16);
            }
            *(uint4*)&As[arow * 40 + ahalf + 0] = *(uint4*)&u[0];
            *(uint4*)&As[arow * 40 + ahalf + 8] = *(uint4*)&u[4];
        }
#pragma unroll
        for (int qq = 0; qq < 2; ++qq) {
            int idx = qq * 256 + t;
            int row = idx >> 2, kc = idx & 3;
            *(uint4*)&Bs[row * 40 + kc * 8] = bv[qq];
        }
        __syncthreads();
        bf16x8 af[4], bfr[4];
#pragma unroll
        for (int i = 0; i < 4; ++i)
            af[i] = *(const bf16x8*)&As[(wr * 64 + i * 16 + lm) * 40 + lq * 8];
#pragma unroll
        for (int j = 0; j < 4; ++j)
            bfr[j] = *(const bf16x8*)&Bs[(wc * 64 + j * 16 + lm) * 40 + lq * 8];
#pragma unroll
        for (int i = 0; i < 4; ++i)
#pragma unroll
            for (int j = 0; j < 4; ++j)
                acc[i][j] = __builtin_amdgcn_mfma_f32_16x16x32_bf16(af[i], bfr[j], acc[i][j], 0, 0, 0);
    }
#pragma unroll
    for (int j = 0; j < 4; ++j) {
        const int gn = n0 + wc * 64 + j * 16 + lm;
        const float bb = bias[gn];
        float ps = 0.0f, pq = 0.0f;
#pragma unroll
        for (int i = 0; i < 4; ++i) {
            const int gm = m0 + wr * 64 + i * 16 + lq * 4;
            f32x4 v = acc[i][j];
#pragma unroll
            for (int r = 0; r < 4; ++r) {
                float val = v[r] + bb;
                C[(size_t)(gm + r) * H_ + gn] = f2bf(val);
                ps += val;
                pq += val * val;
            }
        }
        ps += __shfl_xor(ps, 16); pq += __shfl_xor(pq, 16);
        ps += __shfl_xor(ps, 32); pq += __shfl_xor(pq, 32);
        if (lane < 16) {
            atomicAdd(&ssum[gn], ps);
            atomicAdd(&ssq[gn], pq);
        }
    }
}

// ------------------------------- BN2 + ReLU + transpose, bf16 y2 -> out[B,256,N2] fp32
__global__ __launch_bounds__(256) void bn_out_kernel(
    const ushort_t* __restrict__ y, const float* __restrict__ ssum, const float* __restrict__ ssq,
    const float* __restrict__ g, const float* __restrict__ beta, float* __restrict__ out)
{
    __shared__ float tile[64][65];
    __shared__ float sc[64], sh[64];
    const float invN = 1.0f / (float)ROWS_;
    const int bid = blockIdx.x;
    const int b  = bid >> 8;
    const int nt = (bid >> 2) & 63;
    const int ot = bid & 3;
    const int t = threadIdx.x;
    if (t < 64) {
        int c = ot * 64 + t;
        float mu  = ssum[c] * invN;
        float var = ssq[c] * invN - mu * mu;
        float s   = rsqrtf(var + 1e-3f) * g[c];
        sc[t] = s;
        sh[t] = beta[c] - mu * s;
    }
    __syncthreads();
    const int n0 = nt * 64, o0 = ot * 64;
    const ushort_t* yb = y + ((size_t)b * N2_ + n0) * H_ + o0;
#pragma unroll
    for (int j = 0; j < 8; ++j) {
        int lin = j * 256 + t;
        int nl = lin >> 5, cu = (lin & 31) * 2;
        uint_t u = *(const uint_t*)&yb[(size_t)nl * H_ + cu];
        tile[nl][cu]     = fmaxf(bf2f((ushort_t)(u & 0xffff)) * sc[cu]     + sh[cu],     0.0f);
        tile[nl][cu + 1] = fmaxf(bf2f((ushort_t)(u >> 16))    * sc[cu + 1] + sh[cu + 1], 0.0f);
    }
    __syncthreads();
    float* ob = out + ((size_t)b * H_ + o0) * N2_ + n0;
#pragma unroll
    for (int j = 0; j < 16; ++j) {
        int lin = j * 256 + t;
        int ol = lin >> 6, nl = lin & 63;
        ob[(size_t)ol * N2_ + nl] = tile[nl][ol];
    }
}

// ----------------------------------------------------------------------------
extern "C" void kernel_launch(void* const* d_in, const int* in_sizes, int n_in,
                              void* d_out, int out_size, void* d_ws, size_t ws_size,
                              hipStream_t stream)
{
    (void)in_sizes; (void)n_in; (void)out_size; (void)ws_size;
    const float* points1   = (const float*)d_in[0];
    const float* points2   = (const float*)d_in[1];
    const float* features1 = (const float*)d_in[2];
    const float* features2 = (const float*)d_in[3];
    const float* skipf     = (const float*)d_in[4];
    const float* W1  = (const float*)d_in[5];
    const float* b1  = (const float*)d_in[6];
    const float* g1  = (const float*)d_in[7];
    const float* be1 = (const float*)d_in[8];
    const float* W2  = (const float*)d_in[9];
    const float* b2  = (const float*)d_in[10];
    const float* g2  = (const float*)d_in[11];
    const float* be2 = (const float*)d_in[12];
    float* out = (float*)d_out;

    char* ws = (char*)d_ws;
    float*    s1  = (float*)(ws + 0);
    float*    q1  = (float*)(ws + 1024);
    float*    s2  = (float*)(ws + 2048);
    float*    q2  = (float*)(ws + 3072);
    int*      ind = (int*)(ws + 4096);                 // 393216 B
    float*    wgt = (float*)(ws + 397312);             // 393216 B
    ushort_t* x   = (ushort_t*)(ws + 790528);          // 29,360,128 B (bf16 32768x448)
    float*    y1  = (float*)(ws + 30150656);           // 33,554,432 B (fp32 32768x256)
    ushort_t* W1b = (ushort_t*)(ws + 63705088);        // 229,376 B
    ushort_t* W2b = (ushort_t*)(ws + 63934464);        // 131,072 B
    ushort_t* f1t = (ushort_t*)(ws + 64065536);        // 4,194,304 B (bf16 8x1024x256)
    ushort_t* y2b = x;                                 // alias: x dead after gemm1 (16.7MB <= 29.3MB)

    hipMemsetAsync(ws, 0, 4096, stream);               // zero BN stats

    knn_kernel<<<dim3(2048), dim3(256), 0, stream>>>(points1, points2, ind, wgt);
    transpose_f1<<<dim3(512), dim3(256), 0, stream>>>(features1, f1t);
    convert_w<<<dim3(448), dim3(256), 0, stream>>>(W1, W2, W1b, W2b);
    gather_x<<<dim3(4096), dim3(256), 0, stream>>>(f1t, ind, wgt, x);
    transpose_f2s<<<dim3(1536), dim3(256), 0, stream>>>(features2, skipf, x);

    gemm1_bf16<<<dim3(ROWS_ / 128, 2), dim3(256), 0, stream>>>(x, W1b, b1, y1, s1, q1);
    gemm2_fused<<<dim3(ROWS_ / 128, 2), dim3(256), 0, stream>>>(y1, W2b, b2, s1, q1, g1, be1, y2b, s2, q2);
    bn_out_kernel<<<dim3(2048), dim3(256), 0, stream>>>(y2b, s2, q2, g2, be2, out);
}

// Round 5
// 239.077 us; speedup vs baseline: 2.9011x; 1.0851x over previous
//
#include <hip/hip_runtime.h>
#include <cstdint>
#include <cstddef>

#define B_    8
#define N1_   1024
#define N2_   4096
#define C1_   256
#define C2_   128
#define CS_   64
#define CT_   448
#define H_    256
#define ROWS_ (B_ * N2_)   // 32768

typedef __attribute__((ext_vector_type(8))) short bf16x8;
typedef __attribute__((ext_vector_type(4))) float f32x4;
typedef unsigned short ushort_t;
typedef unsigned int   uint_t;

__device__ __forceinline__ ushort_t f2bf(float f) {
    uint_t u = __float_as_uint(f);
    u = (u + 0x7fffu + ((u >> 16) & 1u)) >> 16;   // RNE
    return (ushort_t)u;
}
__device__ __forceinline__ float bf2f(ushort_t h) {
    return __uint_as_float(((uint_t)h) << 16);
}

// ---------------------------------------------------------------- KNN (K=3)
__global__ __launch_bounds__(256) void knn_kernel(
    const float* __restrict__ p1, const float* __restrict__ p2,
    int* __restrict__ ind, float* __restrict__ wout)
{
#pragma clang fp contract(off)
    __shared__ float4 cand[N1_];
    __shared__ float  pd[256][3];
    __shared__ int    pi[256][3];
    __shared__ float  pd2[64][3];
    __shared__ int    pi2[64][3];
    const int t = threadIdx.x;
    const int b  = blockIdx.x >> 8;
    const int qb = (blockIdx.x & 255) * 16;
    const float* pb1 = p1 + (size_t)b * 3 * N1_;
    for (int i = t; i < N1_; i += 256) {
        float X = pb1[i], Y = pb1[N1_ + i], Z = pb1[2 * N1_ + i];
        cand[i] = make_float4(X, Y, Z, (X * X + Y * Y) + Z * Z);
    }
    const int q = t & 15, split = t >> 4;
    const int n = qb + q;
    const float* pb2 = p2 + (size_t)b * 3 * N2_;
    const float qx = pb2[n], qy = pb2[N2_ + n], qz = pb2[2 * N2_ + n];
    const float s2 = (qx * qx + qy * qy) + qz * qz;
    __syncthreads();
    float d0 = 3.0e38f, d1 = 3.0e38f, d2v = 3.0e38f;
    int   i0 = 0, i1 = 0, i2 = 0;
    const int ibeg = split * 64;
    for (int i = ibeg; i < ibeg + 64; ++i) {
        float4 c = cand[i];
        float dot = (qx * c.x + qy * c.y) + qz * c.z;
        float dd  = (s2 + c.w) - 2.0f * dot;
        float d   = sqrtf(fmaxf(dd, 0.0f));
        if (d < d0)       { d2v = d1; i2 = i1; d1 = d0; i1 = i0; d0 = d; i0 = i; }
        else if (d < d1)  { d2v = d1; i2 = i1; d1 = d;  i1 = i; }
        else if (d < d2v) { d2v = d;  i2 = i; }
    }
    pd[t][0] = d0; pd[t][1] = d1; pd[t][2] = d2v;
    pi[t][0] = i0; pi[t][1] = i1; pi[t][2] = i2;
    __syncthreads();
    if (t < 64) {
        const int qq = t & 15, g = t >> 4;
        float e0 = 3.0e38f, e1 = 3.0e38f, e2 = 3.0e38f;
        int   j0 = 0, j1 = 0, j2 = 0;
#pragma unroll
        for (int s = 0; s < 4; ++s) {
            const int src = (g * 4 + s) * 16 + qq;
#pragma unroll
            for (int r = 0; r < 3; ++r) {
                float d = pd[src][r];
                int   i = pi[src][r];
                if (d < e0)      { e2 = e1; j2 = j1; e1 = e0; j1 = j0; e0 = d; j0 = i; }
                else if (d < e1) { e2 = e1; j2 = j1; e1 = d;  j1 = i; }
                else if (d < e2) { e2 = d;  j2 = i; }
            }
        }
        pd2[t][0] = e0; pd2[t][1] = e1; pd2[t][2] = e2;
        pi2[t][0] = j0; pi2[t][1] = j1; pi2[t][2] = j2;
    }
    __syncthreads();
    if (t < 16) {
        float e0 = 3.0e38f, e1 = 3.0e38f, e2 = 3.0e38f;
        int   j0 = 0, j1 = 0, j2 = 0;
#pragma unroll
        for (int g = 0; g < 4; ++g) {
            const int src = g * 16 + t;
#pragma unroll
            for (int r = 0; r < 3; ++r) {
                float d = pd2[src][r];
                int   i = pi2[src][r];
                if (d < e0)      { e2 = e1; j2 = j1; e1 = e0; j1 = j0; e0 = d; j0 = i; }
                else if (d < e1) { e2 = e1; j2 = j1; e1 = d;  j1 = i; }
                else if (d < e2) { e2 = d;  j2 = i; }
            }
        }
        float inv0 = 1.0f / (e0 + 1e-10f);
        float inv1 = 1.0f / (e1 + 1e-10f);
        float inv2 = 1.0f / (e2 + 1e-10f);
        float s = (inv0 + inv1) + inv2;
        const size_t row = (size_t)b * N2_ + qb + t;
        wout[row * 3 + 0] = inv0 / s;
        wout[row * 3 + 1] = inv1 / s;
        wout[row * 3 + 2] = inv2 / s;
        ind[row * 3 + 0] = j0;
        ind[row * 3 + 1] = j1;
        ind[row * 3 + 2] = j2;
    }
}

// ------------------------------- transpose f1 [B,C1,N1] f32 -> f1t [B,N1,C1] bf16
__global__ __launch_bounds__(256) void transpose_f1(
    const float* __restrict__ f1, ushort_t* __restrict__ f1t)
{
    __shared__ float tile[64][65];
    const int t = threadIdx.x;
    const int bid = blockIdx.x;            // 8b x 4ct x 16nt = 512
    const int b  = bid >> 6;
    const int ct = (bid >> 4) & 3;
    const int nt = bid & 15;
    const int c0 = ct * 64, n0 = nt * 64;
    const float* src = f1 + ((size_t)b * C1_ + c0) * N1_ + n0;
#pragma unroll
    for (int j = 0; j < 16; ++j) {
        int lin = j * 256 + t;
        int ci = lin >> 6, nj = lin & 63;
        tile[ci][nj] = src[(size_t)ci * N1_ + nj];
    }
    __syncthreads();
    ushort_t* dst = f1t + ((size_t)b * N1_ + n0) * C1_ + c0;
#pragma unroll
    for (int j = 0; j < 8; ++j) {
        int lin = j * 256 + t;
        int ni = lin >> 5, cjp = (lin & 31) * 2;
        uint_t u = (uint_t)f2bf(tile[cjp][ni]) | ((uint_t)f2bf(tile[cjp + 1][ni]) << 16);
        *(uint_t*)&dst[(size_t)ni * C1_ + cjp] = u;
    }
}

// ------------------------------- f2/skip transpose directly into x_bf16 tail cols
__global__ __launch_bounds__(256) void transpose_f2s(
    const float* __restrict__ f2, const float* __restrict__ fs, ushort_t* __restrict__ x)
{
    __shared__ float tile[64][65];
    const int t = threadIdx.x;
    const int bid = blockIdx.x;            // 8b x 3ct x 64nt = 1536
    const int b   = bid / 192;
    const int rem = bid - b * 192;
    const int ct  = rem >> 6;
    const int nt  = rem & 63;
    const float* src;
    int coff;
    if (ct < 2) { src = f2 + ((size_t)b * C2_ + ct * 64) * N2_; coff = C1_ + ct * 64; }
    else        { src = fs + (size_t)b * CS_ * N2_;             coff = C1_ + C2_; }
    const int n0 = nt * 64;
#pragma unroll
    for (int j = 0; j < 16; ++j) {
        int lin = j * 256 + t;
        int ci = lin >> 6, nj = lin & 63;
        tile[ci][nj] = src[(size_t)ci * N2_ + n0 + nj];
    }
    __syncthreads();
#pragma unroll
    for (int j = 0; j < 8; ++j) {
        int lin = j * 256 + t;
        int ni = lin >> 5, cjp = (lin & 31) * 2;
        uint_t u = (uint_t)f2bf(tile[cjp][ni]) | ((uint_t)f2bf(tile[cjp + 1][ni]) << 16);
        *(uint_t*)&x[((size_t)b * N2_ + n0 + ni) * CT_ + coff + cjp] = u;
    }
}

// ------------------------------- gather+interp -> x_bf16[:, 0:256]
__global__ __launch_bounds__(256) void gather_x(
    const ushort_t* __restrict__ f1t, const int* __restrict__ ind,
    const float* __restrict__ w, ushort_t* __restrict__ x)
{
    const int t = threadIdx.x;
    const int row = blockIdx.x * 8 + (t >> 5);
    const int b = row >> 12;
    const int cg = (t & 31) * 8;
    const int*   ip = ind + (size_t)row * 3;
    const float* wp = w   + (size_t)row * 3;
    const int i0 = ip[0], i1 = ip[1], i2 = ip[2];
    const float w0 = wp[0], w1 = wp[1], w2 = wp[2];
    const ushort_t* base = f1t + (size_t)b * N1_ * C1_;
    uint4 va = *(const uint4*)(base + (size_t)i0 * C1_ + cg);
    uint4 vb = *(const uint4*)(base + (size_t)i1 * C1_ + cg);
    uint4 vc = *(const uint4*)(base + (size_t)i2 * C1_ + cg);
    const uint_t* pa = (const uint_t*)&va;
    const uint_t* pb = (const uint_t*)&vb;
    const uint_t* pc = (const uint_t*)&vc;
    uint_t out[4];
#pragma unroll
    for (int e = 0; e < 4; ++e) {
        float lo = w0 * bf2f((ushort_t)(pa[e] & 0xffff))
                 + w1 * bf2f((ushort_t)(pb[e] & 0xffff))
                 + w2 * bf2f((ushort_t)(pc[e] & 0xffff));
        float hi = w0 * bf2f((ushort_t)(pa[e] >> 16))
                 + w1 * bf2f((ushort_t)(pb[e] >> 16))
                 + w2 * bf2f((ushort_t)(pc[e] >> 16));
        out[e] = (uint_t)f2bf(lo) | ((uint_t)f2bf(hi) << 16);
    }
    *(uint4*)&x[(size_t)row * CT_ + cg] = *(uint4*)out;
}

// ------------------------------- convert W1/W2 to bf16
__global__ __launch_bounds__(256) void convert_w(
    const float* __restrict__ W1, const float* __restrict__ W2,
    ushort_t* __restrict__ W1b, ushort_t* __restrict__ W2b)
{
    const int i = blockIdx.x * 256 + threadIdx.x;
    if (i < H_ * CT_) W1b[i] = f2bf(W1[i]);
    if (i < H_ * H_)  W2b[i] = f2bf(W2[i]);
}

// ------------------------------- GEMM1: y1b[m,n] = bf16( x[m,:]·W1b[n,:] + b1[n] )
// 128x64 tile, grid(256,4)=1024 blocks (4/CU). Fused BN1 stats on fp32 accum.
__global__ __launch_bounds__(256, 4) void gemm1_bf16(
    const ushort_t* __restrict__ A, const ushort_t* __restrict__ Bw,
    const float* __restrict__ bias, ushort_t* __restrict__ C,
    float* __restrict__ ssum, float* __restrict__ ssq)
{
    __shared__ __align__(16) ushort_t As[128 * 40];
    __shared__ __align__(16) ushort_t Bs[64 * 40];
    const int t = threadIdx.x;
    const int m0 = blockIdx.x * 128;
    const int n0 = blockIdx.y * 64;
    const int lane = t & 63;
    const int wv = t >> 6;
    const int wrow = wv & 1, wcol = wv >> 1;     // 2x2 waves: 64 rows x 32 cols each
    const int lm = lane & 15, lq = lane >> 4;
    const int crow = t >> 2, ckc = (t & 3) * 8;  // staging chunk coords
    f32x4 acc[4][2];
#pragma unroll
    for (int i = 0; i < 4; ++i)
#pragma unroll
        for (int j = 0; j < 2; ++j)
            acc[i][j] = (f32x4){0.f, 0.f, 0.f, 0.f};

    for (int k0 = 0; k0 < CT_; k0 += 32) {
        uint4 a0 = *(const uint4*)(A  + (size_t)(m0 + crow) * CT_ + k0 + ckc);
        uint4 a1 = *(const uint4*)(A  + (size_t)(m0 + 64 + crow) * CT_ + k0 + ckc);
        uint4 b0 = *(const uint4*)(Bw + (size_t)(n0 + crow) * CT_ + k0 + ckc);
        __syncthreads();
        *(uint4*)&As[crow * 40 + ckc]        = a0;
        *(uint4*)&As[(64 + crow) * 40 + ckc] = a1;
        *(uint4*)&Bs[crow * 40 + ckc]        = b0;
        __syncthreads();
        bf16x8 af[4], bfr[2];
#pragma unroll
        for (int i = 0; i < 4; ++i)
            af[i] = *(const bf16x8*)&As[(wrow * 64 + i * 16 + lm) * 40 + lq * 8];
#pragma unroll
        for (int j = 0; j < 2; ++j)
            bfr[j] = *(const bf16x8*)&Bs[(wcol * 32 + j * 16 + lm) * 40 + lq * 8];
#pragma unroll
        for (int i = 0; i < 4; ++i)
#pragma unroll
            for (int j = 0; j < 2; ++j)
                acc[i][j] = __builtin_amdgcn_mfma_f32_16x16x32_bf16(af[i], bfr[j], acc[i][j], 0, 0, 0);
    }
#pragma unroll
    for (int j = 0; j < 2; ++j) {
        const int gn = n0 + wcol * 32 + j * 16 + lm;
        const float bb = bias[gn];
        float ps = 0.0f, pq = 0.0f;
#pragma unroll
        for (int i = 0; i < 4; ++i) {
            const int gm = m0 + wrow * 64 + i * 16 + lq * 4;
            f32x4 v = acc[i][j];
#pragma unroll
            for (int r = 0; r < 4; ++r) {
                float val = v[r] + bb;
                C[(size_t)(gm + r) * H_ + gn] = f2bf(val);
                ps += val;
                pq += val * val;
            }
        }
        ps += __shfl_xor(ps, 16); pq += __shfl_xor(pq, 16);
        ps += __shfl_xor(ps, 32); pq += __shfl_xor(pq, 32);
        if (lane < 16) {
            atomicAdd(&ssum[gn], ps);
            atomicAdd(&ssq[gn], pq);
        }
    }
}

// ------------------------------- GEMM2: A = BN1(y1b bf16)+ReLU in staging.
// Out: y2 bf16 + fused BN2 stats (stats on fp32 accumulators).
__global__ __launch_bounds__(256, 4) void gemm2_fused(
    const ushort_t* __restrict__ A, const ushort_t* __restrict__ Bw,
    const float* __restrict__ bias,
    const float* __restrict__ s1, const float* __restrict__ q1,
    const float* __restrict__ g1, const float* __restrict__ be1,
    ushort_t* __restrict__ C, float* __restrict__ ssum, float* __restrict__ ssq)
{
    __shared__ __align__(16) ushort_t As[128 * 40];
    __shared__ __align__(16) ushort_t Bs[64 * 40];
    __shared__ float sc[H_], sh[H_];
    const int t = threadIdx.x;
    const int m0 = blockIdx.x * 128;
    const int n0 = blockIdx.y * 64;
    const int lane = t & 63;
    const int wv = t >> 6;
    const int wrow = wv & 1, wcol = wv >> 1;
    const int lm = lane & 15, lq = lane >> 4;
    const int crow = t >> 2, ckc = (t & 3) * 8;
    {
        const float invN = 1.0f / (float)ROWS_;
        float mu  = s1[t] * invN;
        float var = q1[t] * invN - mu * mu;
        float s   = rsqrtf(var + 1e-3f) * g1[t];
        sc[t] = s;
        sh[t] = be1[t] - mu * s;
    }
    f32x4 acc[4][2];
#pragma unroll
    for (int i = 0; i < 4; ++i)
#pragma unroll
        for (int j = 0; j < 2; ++j)
            acc[i][j] = (f32x4){0.f, 0.f, 0.f, 0.f};

    for (int k0 = 0; k0 < H_; k0 += 32) {
        uint4 a0 = *(const uint4*)(A  + (size_t)(m0 + crow) * H_ + k0 + ckc);
        uint4 a1 = *(const uint4*)(A  + (size_t)(m0 + 64 + crow) * H_ + k0 + ckc);
        uint4 b0 = *(const uint4*)(Bw + (size_t)(n0 + crow) * H_ + k0 + ckc);
        __syncthreads();   // also guards sc/sh on first iteration
        {
            const uint_t* pa0 = (const uint_t*)&a0;
            const uint_t* pa1 = (const uint_t*)&a1;
            uint_t u0[4], u1[4];
#pragma unroll
            for (int e = 0; e < 4; ++e) {
                const int cb = k0 + ckc + 2 * e;
                float l0 = fmaxf(bf2f((ushort_t)(pa0[e] & 0xffff)) * sc[cb]     + sh[cb],     0.0f);
                float h0 = fmaxf(bf2f((ushort_t)(pa0[e] >> 16))    * sc[cb + 1] + sh[cb + 1], 0.0f);
                float l1 = fmaxf(bf2f((ushort_t)(pa1[e] & 0xffff)) * sc[cb]     + sh[cb],     0.0f);
                float h1 = fmaxf(bf2f((ushort_t)(pa1[e] >> 16))    * sc[cb + 1] + sh[cb + 1], 0.0f);
                u0[e] = (uint_t)f2bf(l0) | ((uint_t)f2bf(h0) << 16);
                u1[e] = (uint_t)f2bf(l1) | ((uint_t)f2bf(h1) << 16);
            }
            *(uint4*)&As[crow * 40 + ckc]        = *(uint4*)u0;
            *(uint4*)&As[(64 + crow) * 40 + ckc] = *(uint4*)u1;
        }
        *(uint4*)&Bs[crow * 40 + ckc] = b0;
        __syncthreads();
        bf16x8 af[4], bfr[2];
#pragma unroll
        for (int i = 0; i < 4; ++i)
            af[i] = *(const bf16x8*)&As[(wrow * 64 + i * 16 + lm) * 40 + lq * 8];
#pragma unroll
        for (int j = 0; j < 2; ++j)
            bfr[j] = *(const bf16x8*)&Bs[(wcol * 32 + j * 16 + lm) * 40 + lq * 8];
#pragma unroll
        for (int i = 0; i < 4; ++i)
#pragma unroll
            for (int j = 0; j < 2; ++j)
                acc[i][j] = __builtin_amdgcn_mfma_f32_16x16x32_bf16(af[i], bfr[j], acc[i][j], 0, 0, 0);
    }
#pragma unroll
    for (int j = 0; j < 2; ++j) {
        const int gn = n0 + wcol * 32 + j * 16 + lm;
        const float bb = bias[gn];
        float ps = 0.0f, pq = 0.0f;
#pragma unroll
        for (int i = 0; i < 4; ++i) {
            const int gm = m0 + wrow * 64 + i * 16 + lq * 4;
            f32x4 v = acc[i][j];
#pragma unroll
            for (int r = 0; r < 4; ++r) {
                float val = v[r] + bb;
                C[(size_t)(gm + r) * H_ + gn] = f2bf(val);
                ps += val;
                pq += val * val;
            }
        }
        ps += __shfl_xor(ps, 16); pq += __shfl_xor(pq, 16);
        ps += __shfl_xor(ps, 32); pq += __shfl_xor(pq, 32);
        if (lane < 16) {
            atomicAdd(&ssum[gn], ps);
            atomicAdd(&ssq[gn], pq);
        }
    }
}

// ------------------------------- BN2 + ReLU + transpose, bf16 y2 -> out[B,256,N2] fp32
__global__ __launch_bounds__(256) void bn_out_kernel(
    const ushort_t* __restrict__ y, const float* __restrict__ ssum, const float* __restrict__ ssq,
    const float* __restrict__ g, const float* __restrict__ beta, float* __restrict__ out)
{
    __shared__ float tile[64][65];
    __shared__ float sc[64], sh[64];
    const float invN = 1.0f / (float)ROWS_;
    const int bid = blockIdx.x;
    const int b  = bid >> 8;
    const int nt = (bid >> 2) & 63;
    const int ot = bid & 3;
    const int t = threadIdx.x;
    if (t < 64) {
        int c = ot * 64 + t;
        float mu  = ssum[c] * invN;
        float var = ssq[c] * invN - mu * mu;
        float s   = rsqrtf(var + 1e-3f) * g[c];
        sc[t] = s;
        sh[t] = beta[c] - mu * s;
    }
    __syncthreads();
    const int n0 = nt * 64, o0 = ot * 64;
    const ushort_t* yb = y + ((size_t)b * N2_ + n0) * H_ + o0;
#pragma unroll
    for (int j = 0; j < 8; ++j) {
        int lin = j * 256 + t;
        int nl = lin >> 5, cu = (lin & 31) * 2;
        uint_t u = *(const uint_t*)&yb[(size_t)nl * H_ + cu];
        tile[nl][cu]     = fmaxf(bf2f((ushort_t)(u & 0xffff)) * sc[cu]     + sh[cu],     0.0f);
        tile[nl][cu + 1] = fmaxf(bf2f((ushort_t)(u >> 16))    * sc[cu + 1] + sh[cu + 1], 0.0f);
    }
    __syncthreads();
    float* ob = out + ((size_t)b * H_ + o0) * N2_ + n0;
#pragma unroll
    for (int j = 0; j < 16; ++j) {
        int lin = j * 256 + t;
        int ol = lin >> 6, nl = lin & 63;
        ob[(size_t)ol * N2_ + nl] = tile[nl][ol];
    }
}

// ----------------------------------------------------------------------------
extern "C" void kernel_launch(void* const* d_in, const int* in_sizes, int n_in,
                              void* d_out, int out_size, void* d_ws, size_t ws_size,
                              hipStream_t stream)
{
    (void)in_sizes; (void)n_in; (void)out_size; (void)ws_size;
    const float* points1   = (const float*)d_in[0];
    const float* points2   = (const float*)d_in[1];
    const float* features1 = (const float*)d_in[2];
    const float* features2 = (const float*)d_in[3];
    const float* skipf     = (const float*)d_in[4];
    const float* W1  = (const float*)d_in[5];
    const float* b1  = (const float*)d_in[6];
    const float* g1  = (const float*)d_in[7];
    const float* be1 = (const float*)d_in[8];
    const float* W2  = (const float*)d_in[9];
    const float* b2  = (const float*)d_in[10];
    const float* g2  = (const float*)d_in[11];
    const float* be2 = (const float*)d_in[12];
    float* out = (float*)d_out;

    char* ws = (char*)d_ws;
    float*    s1  = (float*)(ws + 0);
    float*    q1  = (float*)(ws + 1024);
    float*    s2  = (float*)(ws + 2048);
    float*    q2  = (float*)(ws + 3072);
    int*      ind = (int*)(ws + 4096);                 // 393216 B
    float*    wgt = (float*)(ws + 397312);             // 393216 B
    ushort_t* x   = (ushort_t*)(ws + 790528);          // 29,360,128 B (bf16 32768x448)
    ushort_t* y1b = (ushort_t*)(ws + 30150656);        // 16,777,216 B (bf16 32768x256)
    ushort_t* W1b = (ushort_t*)(ws + 63705088);        // 229,376 B
    ushort_t* W2b = (ushort_t*)(ws + 63934464);        // 131,072 B
    ushort_t* f1t = (ushort_t*)(ws + 64065536);        // 4,194,304 B (bf16 8x1024x256)
    ushort_t* y2b = x;                                 // alias: x dead after gemm1

    hipMemsetAsync(ws, 0, 4096, stream);               // zero BN stats

    knn_kernel<<<dim3(2048), dim3(256), 0, stream>>>(points1, points2, ind, wgt);
    transpose_f1<<<dim3(512), dim3(256), 0, stream>>>(features1, f1t);
    convert_w<<<dim3(448), dim3(256), 0, stream>>>(W1, W2, W1b, W2b);
    gather_x<<<dim3(4096), dim3(256), 0, stream>>>(f1t, ind, wgt, x);
    transpose_f2s<<<dim3(1536), dim3(256), 0, stream>>>(features2, skipf, x);

    gemm1_bf16<<<dim3(ROWS_ / 128, 4), dim3(256), 0, stream>>>(x, W1b, b1, y1b, s1, q1);
    gemm2_fused<<<dim3(ROWS_ / 128, 4), dim3(256), 0, stream>>>(y1b, W2b, b2, s1, q1, g1, be1, y2b, s2, q2);
    bn_out_kernel<<<dim3(2048), dim3(256), 0, stream>>>(y2b, s2, q2, g2, be2, out);
}